// Round 2
// baseline (237.777 us; speedup 1.0000x reference)
//
#include <hip/hip_runtime.h>

#define L_DIM 2048
#define B_DIM 8
#define DD    1024
#define M_DIM 16384     // L*B
#define N_DIM 3072      // 3*D
#define K_DIM 1024
#define CH    8192      // B*D channels
#define CH8   1024      // CH/8 (vec8 units per l-step)
#define NSEG  128
#define LSEG  16
#define LN_EPS 1e-5f

typedef __attribute__((ext_vector_type(8))) short bf16x8;
typedef __attribute__((ext_vector_type(8))) unsigned short u16x8;
typedef __attribute__((ext_vector_type(4))) float f32x4;

__device__ __forceinline__ unsigned short f2bf(float f){
  unsigned u = __float_as_uint(f);
  u += 0x7fffu + ((u >> 16) & 1u);
  return (unsigned short)(u >> 16);
}
__device__ __forceinline__ float bf2f(unsigned short h){
  return __uint_as_float(((unsigned)h) << 16);
}
__device__ __forceinline__ float fsigmoid(float z){ return 1.0f/(1.0f + __expf(-z)); }
__device__ __forceinline__ float ftanh(float z){ return 1.0f - 2.0f/(1.0f + __expf(2.0f*z)); }

// ------- LayerNorm: wave-per-row, 4 rows/block, no barriers -------
__global__ __launch_bounds__(256) void ln_kernel(const float* __restrict__ x,
                                                 const float* __restrict__ g,
                                                 const float* __restrict__ bta,
                                                 unsigned short* __restrict__ xn)
{
  int tid  = threadIdx.x;
  int wave = tid >> 6, lane = tid & 63;
  int row  = blockIdx.x * 4 + wave;
  const float4* xr = (const float4*)(x + (size_t)row * DD);
  float4 v[4];
  #pragma unroll
  for (int k = 0; k < 4; k++) v[k] = xr[lane + k * 64];
  float s = 0.f, sq = 0.f;
  #pragma unroll
  for (int k = 0; k < 4; k++) {
    s  += v[k].x + v[k].y + v[k].z + v[k].w;
    sq += v[k].x*v[k].x + v[k].y*v[k].y + v[k].z*v[k].z + v[k].w*v[k].w;
  }
  #pragma unroll
  for (int off = 32; off > 0; off >>= 1) {
    s  += __shfl_down(s,  off, 64);
    sq += __shfl_down(sq, off, 64);
  }
  s  = __shfl(s,  0, 64);
  sq = __shfl(sq, 0, 64);
  float mean = s * (1.0f / DD);
  float var  = sq * (1.0f / DD) - mean * mean;
  float rstd = rsqrtf(var + LN_EPS);
  ushort4* xo = (ushort4*)(xn + (size_t)row * DD);
  #pragma unroll
  for (int k = 0; k < 4; k++) {
    float4 gg = ((const float4*)g)[lane + k * 64];
    float4 bb = ((const float4*)bta)[lane + k * 64];
    ushort4 o;
    o.x = f2bf((v[k].x - mean) * rstd * gg.x + bb.x);
    o.y = f2bf((v[k].y - mean) * rstd * gg.y + bb.y);
    o.z = f2bf((v[k].z - mean) * rstd * gg.z + bb.z);
    o.w = f2bf((v[k].w - mean) * rstd * gg.w + bb.w);
    xo[lane + k * 64] = o;
  }
}

// ---------------- W fp32 [3072,1024] -> bf16 same layout ----------------
__global__ __launch_bounds__(256) void wconv_kernel(const float* __restrict__ W,
                                                    unsigned short* __restrict__ wb)
{
  int gid = blockIdx.x * 256 + threadIdx.x;
  float4 v = ((const float4*)W)[gid];
  ushort4 o;
  o.x = f2bf(v.x); o.y = f2bf(v.y); o.z = f2bf(v.z); o.w = f2bf(v.w);
  ((ushort4*)wb)[gid] = o;
}

// ---------------- GEMM: ufr = xn * W^T + b, fused activations ----------------
// 256x256 tile, 8 waves (2Mx4N), BK=64, 4-phase/K-tile, counted vmcnt(6).
// Fragment loads are inline-asm ds_read_b128 (NOT visible to the compiler's
// alias analysis) so hipcc cannot insert vmcnt(0) drains between the
// global_load_lds prefetch stream and the LDS reads (the R1 failure mode).
#define BM 256
#define BN 256
#define BK 64
#define NT 16          // K_DIM / BK
#define LDPE 264       // epilogue LDS leading dim (shorts)

#define GLDS16(gp, lp) __builtin_amdgcn_global_load_lds( \
    (const __attribute__((address_space(1))) void*)(gp), \
    (__attribute__((address_space(3))) void*)(lp), 16, 0, 0)

#define SBAR()   __builtin_amdgcn_s_barrier()
#define SCHED0() __builtin_amdgcn_sched_barrier(0)
#define WAIT_LGKM0() do { asm volatile("s_waitcnt lgkmcnt(0)" ::: "memory"); SCHED0(); } while(0)
#define WAIT_VM(N)   do { asm volatile("s_waitcnt vmcnt(" #N ")" ::: "memory"); SCHED0(); } while(0)

// raw ds_read_b128: no "memory" clobber on purpose (see header comment).
#define DSR(dst, addr, IMM) \
  asm volatile("ds_read_b128 %0, %1 offset:" #IMM : "=v"(dst) : "v"(addr))

__global__ __launch_bounds__(512, 2) void gemm_gates(const unsigned short* __restrict__ Ag,
                                                     const unsigned short* __restrict__ Bg,
                                                     const float* __restrict__ bias,
                                                     unsigned short* __restrict__ u_t,
                                                     unsigned short* __restrict__ f_g,
                                                     unsigned short* __restrict__ r_g)
{
  // LDS: A dbuf = [2][256][64] shorts (bytes 0..65535), B dbuf (bytes 65536..131071)
  __shared__ unsigned short smem[65536];   // 128 KiB
  const int tid  = threadIdx.x;
  const int wave = tid >> 6, lane = tid & 63;
  const int wm = wave >> 2, wn = wave & 3;          // 2 x 4 wave grid
  const int r8 = lane >> 3;
  const int sch = (lane & 7) ^ r8;                  // inverse-swizzled source chunk
  const int fm = lane & 15, quad = lane >> 4, f7 = fm & 7;
  const int bm0 = blockIdx.x * BM, bn0 = blockIdx.y * BN;

  f32x4 zero = {0.f, 0.f, 0.f, 0.f};
  f32x4 acc[8][4];
  #pragma unroll
  for (int i = 0; i < 8; i++)
    #pragma unroll
    for (int j = 0; j < 4; j++) acc[i][j] = zero;

// stage one half-tile (128 rows x 64 cols) = 2 global_load_lds per wave.
// LDS dest linear; global source chunk pre-swizzled (chunk ^ (row&7)).
#define STAGE_A(BUF, T, HALF) do { \
  GLDS16(Ag + (size_t)(bm0 + (HALF)*128 + wave*16 + 0 + r8) * K_DIM + ((T)*BK + sch*8), \
         &smem[(BUF)*16384 + ((HALF)*128 + wave*16 + 0) * 64]); \
  GLDS16(Ag + (size_t)(bm0 + (HALF)*128 + wave*16 + 8 + r8) * K_DIM + ((T)*BK + sch*8), \
         &smem[(BUF)*16384 + ((HALF)*128 + wave*16 + 8) * 64]); \
} while(0)

#define STAGE_B(BUF, T, HALF) do { \
  GLDS16(Bg + (size_t)(bn0 + (HALF)*128 + wave*16 + 0 + r8) * K_DIM + ((T)*BK + sch*8), \
         &smem[32768 + (BUF)*16384 + ((HALF)*128 + wave*16 + 0) * 64]); \
  GLDS16(Bg + (size_t)(bn0 + (HALF)*128 + wave*16 + 8 + r8) * K_DIM + ((T)*BK + sch*8), \
         &smem[32768 + (BUF)*16384 + ((HALF)*128 + wave*16 + 8) * 64]); \
} while(0)

// fragment reads, asm ds_read_b128, read-side swizzle folded into base addrs.
// A byte addr = cb*32768 + row*128 + slot*16; slot(kk=1) = slot(kk=0)^4 -> addr^64
#define RD_A(CBB, MH) do { \
  unsigned a0 = (CBB) + aBase + (MH)*8192; unsigned a1 = a0 ^ 64u; \
  DSR(a_[0][0], a0, 0);    DSR(a_[0][1], a1, 0); \
  DSR(a_[1][0], a0, 2048); DSR(a_[1][1], a1, 2048); \
  DSR(a_[2][0], a0, 4096); DSR(a_[2][1], a1, 4096); \
  DSR(a_[3][0], a0, 6144); DSR(a_[3][1], a1, 6144); \
} while(0)

#define RD_B(CBB, NH, D) do { \
  unsigned b0a = (CBB) + bBase + (NH)*4096; unsigned b1a = b0a ^ 64u; \
  DSR(D[0][0], b0a, 0);    DSR(D[0][1], b1a, 0); \
  DSR(D[1][0], b0a, 2048); DSR(D[1][1], b1a, 2048); \
} while(0)

#define QMFMA(MH, NH, BREG) do { \
  _Pragma("unroll") for (int i_ = 0; i_ < 4; ++i_) \
  _Pragma("unroll") for (int j_ = 0; j_ < 2; ++j_) \
  _Pragma("unroll") for (int kk_ = 0; kk_ < 2; ++kk_) \
    acc[(MH)*4 + i_][(NH)*2 + j_] = __builtin_amdgcn_mfma_f32_16x16x32_bf16( \
        a_[i_][kk_], BREG[j_][kk_], acc[(MH)*4 + i_][(NH)*2 + j_], 0, 0, 0); \
} while(0)

  bf16x8 a_[4][2], b0_[2][2], b1_[2][2];
  const unsigned slot0 = (unsigned)((quad ^ f7) << 4);
  const unsigned aBase = (unsigned)((wm * 128 + fm) * 128) + slot0;
  const unsigned bBase = 65536u + (unsigned)((wn * 64 + fm) * 128) + slot0;

  // ---- prologue: tile0 (A,B), tile1 B both halves + A half0 ----
  STAGE_A(0, 0, 0); STAGE_A(0, 0, 1);
  STAGE_B(0, 0, 0); STAGE_B(0, 0, 1);
  STAGE_B(1, 1, 0); STAGE_B(1, 1, 1);
  STAGE_A(1, 1, 0);
  WAIT_VM(6);            // tile0's 8 loads landed; tile1's 6 still in flight
  SBAR();

  #pragma unroll
  for (int t = 0; t < NT; ++t) {
    const int cb = t & 1, nb = cb ^ 1;
    const unsigned cbB = (unsigned)(cb * 32768);
    // ---- P0: read A(mh0)+B(nh0); stage (t+1).A-half1 (h0 staged at t-1 P3) ----
    RD_A(cbB, 0);
    RD_B(cbB, 0, b0_);
    if (t + 1 < NT) STAGE_A(nb, t + 1, 1);
    SCHED0(); SBAR();
    WAIT_LGKM0();
    __builtin_amdgcn_s_setprio(1);
    QMFMA(0, 0, b0_);
    __builtin_amdgcn_s_setprio(0);
    SBAR();
    // ---- P1: read B(nh1) ----
    RD_B(cbB, 1, b1_);
    SCHED0(); SBAR();
    WAIT_LGKM0();
    __builtin_amdgcn_s_setprio(1);
    QMFMA(0, 1, b1_);
    __builtin_amdgcn_s_setprio(0);
    SBAR();
    // ---- P2: read A(mh1); stage (t+2).B-half0 (cb.B free after P1 barrier) ----
    RD_A(cbB, 1);
    if (t + 2 < NT) STAGE_B(cb, t + 2, 0);
    SCHED0(); SBAR();
    WAIT_LGKM0();
    __builtin_amdgcn_s_setprio(1);
    QMFMA(1, 1, b1_);
    __builtin_amdgcn_s_setprio(0);
    SBAR();
    // ---- P3: stage (t+2).B-half1 + (t+2).A-half0 (cb.A free after P2 barrier);
    //      register-only MFMA (no leading barrier); counted vmcnt AFTER MFMA ----
    if (t + 2 < NT) { STAGE_B(cb, t + 2, 1); STAGE_A(cb, t + 2, 0); }
    SCHED0();
    __builtin_amdgcn_s_setprio(1);
    QMFMA(1, 0, b0_);
    __builtin_amdgcn_s_setprio(0);
    if (t < NT - 2)       WAIT_VM(6);   // drains tile t+1 fully; leaves t+2's 6
    else if (t == NT - 2) WAIT_VM(0);   // tail: tile15 landed
    SBAR();
  }
  __syncthreads();

  // ---- epilogue: bias + activation, LDS transpose in 2 halves, coalesced out ----
  const int slice = bn0 >> 10;
  const int nd0   = bn0 & 1023;
  unsigned short* dst = (slice == 0) ? u_t : ((slice == 1) ? f_g : r_g);

  #pragma unroll
  for (int h = 0; h < 2; ++h) {
    if (wm == h) {
      #pragma unroll
      for (int ni = 0; ni < 4; ++ni) {
        int lcol = wn * 64 + ni * 16 + fm;
        float bia = bias[bn0 + lcol];
        #pragma unroll
        for (int mi = 0; mi < 8; ++mi) {
          #pragma unroll
          for (int reg = 0; reg < 4; ++reg) {
            int lrow = mi * 16 + quad * 4 + reg;          // 0..127 within half
            float v = acc[mi][ni][reg] + bia;
            float act = (slice == 0) ? ftanh(v) : fsigmoid(v);
            smem[lrow * LDPE + lcol] = f2bf(act);
          }
        }
      }
    }
    __syncthreads();
    #pragma unroll
    for (int it = 0; it < 8; ++it) {
      int row = it * 16 + (tid >> 5);
      int cc  = (tid & 31) * 8;
      u16x8 v = *(const u16x8*)&smem[row * LDPE + cc];
      *(u16x8*)(dst + (size_t)(bm0 + h * 128 + row) * DD + nd0 + cc) = v;
    }
    __syncthreads();
  }
}

// ---- scan pass 1: per-segment affine summary, vec8 channels, 16B loads ----
__global__ __launch_bounds__(256) void scan_pass1(const unsigned short* __restrict__ f_g,
                                                  const unsigned short* __restrict__ u_t,
                                                  unsigned short* __restrict__ P,
                                                  unsigned short* __restrict__ E)
{
  int vc8 = blockIdx.x * 256 + threadIdx.x;   // 0..1023
  int seg = blockIdx.y;                       // 0..127
  const u16x8* f8 = (const u16x8*)f_g;
  const u16x8* u8 = (const u16x8*)u_t;
  size_t g = (size_t)(seg * LSEG) * CH8 + vc8;
  float p[8], e[8];
  #pragma unroll
  for (int k = 0; k < 8; k++) { p[k] = 1.f; e[k] = 0.f; }
  #pragma unroll 4
  for (int i = 0; i < LSEG; i++) {
    u16x8 ff = f8[g];
    u16x8 uu = u8[g];
    #pragma unroll
    for (int k = 0; k < 8; k++) {
      float fv = bf2f(ff[k]);
      e[k] = fv * e[k] + (1.f - fv) * bf2f(uu[k]);
      p[k] *= fv;
    }
    g += CH8;
  }
  u16x8 pv, ev;
  #pragma unroll
  for (int k = 0; k < 8; k++) { pv[k] = f2bf(p[k]); ev[k] = f2bf(e[k]); }
  ((u16x8*)P)[(size_t)seg * CH8 + vc8] = pv;
  ((u16x8*)E)[(size_t)seg * CH8 + vc8] = ev;
}

// ---- scan pass 2: scan 128 segment summaries per channel ----
__global__ __launch_bounds__(128) void scan_pass2(const unsigned short* __restrict__ P,
                                                  const unsigned short* __restrict__ E,
                                                  const float* __restrict__ c0,
                                                  float* __restrict__ Cini,
                                                  float* __restrict__ lastc)
{
  int ch = blockIdx.x * 128 + threadIdx.x;    // 64 blocks x 128
  float c = c0[ch];
  #pragma unroll 8
  for (int s = 0; s < NSEG; s++) {
    Cini[(size_t)s * CH + ch] = c;
    c = bf2f(P[(size_t)s * CH + ch]) * c + bf2f(E[(size_t)s * CH + ch]);
  }
  lastc[ch] = c;
}

// ---- scan pass 3: replay with true init + fused output, vec8, 16B loads ----
__global__ __launch_bounds__(256) void scan_pass3(const unsigned short* __restrict__ f_g,
                                                  const unsigned short* __restrict__ u_t,
                                                  const unsigned short* __restrict__ r_g,
                                                  const float* __restrict__ x,
                                                  const unsigned short* __restrict__ xn,
                                                  const float* __restrict__ Cini,
                                                  float* __restrict__ out)
{
  int vc8 = blockIdx.x * 256 + threadIdx.x;   // 0..1023
  int seg = blockIdx.y;                       // 0..127
  const u16x8* f8 = (const u16x8*)f_g;
  const u16x8* u8 = (const u16x8*)u_t;
  const u16x8* r8 = (const u16x8*)r_g;
  const u16x8* n8 = (const u16x8*)xn;
  const float4* x4 = (const float4*)x;
  float4* o4 = (float4*)out;
  float c[8];
  {
    const float4* C4 = (const float4*)Cini;
    size_t ci = (size_t)seg * (CH / 4) + (size_t)vc8 * 2;
    float4 ca = C4[ci], cb = C4[ci + 1];
    c[0]=ca.x; c[1]=ca.y; c[2]=ca.z; c[3]=ca.w;
    c[4]=cb.x; c[5]=cb.y; c[6]=cb.z; c[7]=cb.w;
  }
  size_t g = (size_t)(seg * LSEG) * CH8 + vc8;
  #pragma unroll 2
  for (int i = 0; i < LSEG; i++) {
    u16x8 ff = f8[g];
    u16x8 uu = u8[g];
    u16x8 rr = r8[g];
    u16x8 nn = n8[g];
    size_t xi = g * 2;                 // float4 index (8 floats = 2 float4)
    float4 xa = x4[xi], xb = x4[xi + 1];
    float ov[8];
    #pragma unroll
    for (int k = 0; k < 8; k++) {
      float fv = bf2f(ff[k]);
      c[k] = fv * c[k] + (1.f - fv) * bf2f(uu[k]);
      float rv = bf2f(rr[k]);
      ov[k] = rv * ftanh(c[k]) + (1.f - rv) * bf2f(nn[k]);
    }
    o4[xi]     = (float4){xa.x + ov[0], xa.y + ov[1], xa.z + ov[2], xa.w + ov[3]};
    o4[xi + 1] = (float4){xb.x + ov[4], xb.y + ov[5], xb.z + ov[6], xb.w + ov[7]};
    g += CH8;
  }
}

extern "C" void kernel_launch(void* const* d_in, const int* in_sizes, int n_in,
                              void* d_out, int out_size, void* d_ws, size_t ws_size,
                              hipStream_t stream) {
  const float* x    = (const float*)d_in[0];
  const float* c0   = (const float*)d_in[1];
  const float* W    = (const float*)d_in[2];
  const float* bias = (const float*)d_in[3];
  const float* ln_g = (const float*)d_in[4];
  const float* ln_b = (const float*)d_in[5];
  float* out = (float*)d_out;

  char* ws = (char*)d_ws;
  unsigned short* xn  = (unsigned short*)(ws);                 // 33,554,432 B
  unsigned short* wb  = (unsigned short*)(ws + 33554432ULL);   //  6,291,456 B (dead after gemm)
  unsigned short* u_t = (unsigned short*)(ws + 39845888ULL);   // 33,554,432 B
  unsigned short* f_g = (unsigned short*)(ws + 73400320ULL);   // 33,554,432 B
  unsigned short* r_g = (unsigned short*)(ws + 106954752ULL);  // 33,554,432 B
  // P,E (bf16, 2 MB each) reuse wb's region after gemm completes:
  unsigned short* Pseg = (unsigned short*)(ws + 33554432ULL);  // 2,097,152 B
  unsigned short* Eseg = (unsigned short*)(ws + 35651584ULL);  // 2,097,152 B
  float* Cini = (float*)(ws + 140509184ULL);                   // 4,194,304 B (ends 144,703,488)

  ln_kernel   <<<M_DIM / 4, 256, 0, stream>>>(x, ln_g, ln_b, xn);
  wconv_kernel<<<N_DIM, 256, 0, stream>>>(W, wb);
  gemm_gates  <<<dim3(M_DIM / BM, N_DIM / BN), 512, 0, stream>>>(xn, wb, bias, u_t, f_g, r_g);
  scan_pass1  <<<dim3(CH8 / 256, NSEG), 256, 0, stream>>>(f_g, u_t, Pseg, Eseg);
  scan_pass2  <<<CH / 128, 128, 0, stream>>>(Pseg, Eseg, c0, Cini, out + (size_t)M_DIM * DD);
  scan_pass3  <<<dim3(CH8 / 256, NSEG), 256, 0, stream>>>(f_g, u_t, r_g, x, xn, Cini, out);
}

// Round 3
// 232.461 us; speedup vs baseline: 1.0229x; 1.0229x over previous
//
#include <hip/hip_runtime.h>

#define L_DIM 2048
#define B_DIM 8
#define DD    1024
#define M_DIM 16384     // L*B
#define N_DIM 3072      // 3*D
#define K_DIM 1024
#define CH    8192      // B*D channels
#define CH8   1024      // CH/8 (vec8 units per l-step)
#define NSEG  128
#define LSEG  16
#define LN_EPS 1e-5f

typedef __attribute__((ext_vector_type(8))) short bf16x8;
typedef __attribute__((ext_vector_type(8))) unsigned short u16x8;
typedef __attribute__((ext_vector_type(4))) float f32x4;

__device__ __forceinline__ unsigned short f2bf(float f){
  unsigned u = __float_as_uint(f);
  u += 0x7fffu + ((u >> 16) & 1u);
  return (unsigned short)(u >> 16);
}
__device__ __forceinline__ float bf2f(unsigned short h){
  return __uint_as_float(((unsigned)h) << 16);
}
__device__ __forceinline__ float fsigmoid(float z){ return 1.0f/(1.0f + __expf(-z)); }
__device__ __forceinline__ float ftanh(float z){ return 1.0f - 2.0f/(1.0f + __expf(2.0f*z)); }

// ------- LayerNorm: wave-per-row, 4 rows/block, no barriers -------
__global__ __launch_bounds__(256) void ln_kernel(const float* __restrict__ x,
                                                 const float* __restrict__ g,
                                                 const float* __restrict__ bta,
                                                 unsigned short* __restrict__ xn)
{
  int tid  = threadIdx.x;
  int wave = tid >> 6, lane = tid & 63;
  int row  = blockIdx.x * 4 + wave;
  const float4* xr = (const float4*)(x + (size_t)row * DD);
  float4 v[4];
  #pragma unroll
  for (int k = 0; k < 4; k++) v[k] = xr[lane + k * 64];
  float s = 0.f, sq = 0.f;
  #pragma unroll
  for (int k = 0; k < 4; k++) {
    s  += v[k].x + v[k].y + v[k].z + v[k].w;
    sq += v[k].x*v[k].x + v[k].y*v[k].y + v[k].z*v[k].z + v[k].w*v[k].w;
  }
  #pragma unroll
  for (int off = 32; off > 0; off >>= 1) {
    s  += __shfl_down(s,  off, 64);
    sq += __shfl_down(sq, off, 64);
  }
  s  = __shfl(s,  0, 64);
  sq = __shfl(sq, 0, 64);
  float mean = s * (1.0f / DD);
  float var  = sq * (1.0f / DD) - mean * mean;
  float rstd = rsqrtf(var + LN_EPS);
  ushort4* xo = (ushort4*)(xn + (size_t)row * DD);
  #pragma unroll
  for (int k = 0; k < 4; k++) {
    float4 gg = ((const float4*)g)[lane + k * 64];
    float4 bb = ((const float4*)bta)[lane + k * 64];
    ushort4 o;
    o.x = f2bf((v[k].x - mean) * rstd * gg.x + bb.x);
    o.y = f2bf((v[k].y - mean) * rstd * gg.y + bb.y);
    o.z = f2bf((v[k].z - mean) * rstd * gg.z + bb.z);
    o.w = f2bf((v[k].w - mean) * rstd * gg.w + bb.w);
    xo[lane + k * 64] = o;
  }
}

// ---------------- W fp32 [3072,1024] -> bf16 same layout ----------------
__global__ __launch_bounds__(256) void wconv_kernel(const float* __restrict__ W,
                                                    unsigned short* __restrict__ wb)
{
  int gid = blockIdx.x * 256 + threadIdx.x;
  float4 v = ((const float4*)W)[gid];
  ushort4 o;
  o.x = f2bf(v.x); o.y = f2bf(v.y); o.z = f2bf(v.z); o.w = f2bf(v.w);
  ((ushort4*)wb)[gid] = o;
}

// ---------------- GEMM: ufr = xn * W^T + b, fused activations ----------------
// 256x256 tile, 8 waves (2Mx4N), BK=64. Quadrant Gray-cycle Q00->Q01->Q11->Q10
// with ROLLING fragment replacement: ds_reads issue INSIDE the MFMA clusters
// (reads for the next quadrant replace registers right after their last use),
// so LDS service time hides under the matrix pipe (the m196 interleave lever).
// One barrier per phase; single counted WAIT_VM(6) per K-tile at P3.
#define BM 256
#define BN 256
#define BK 64
#define NT 16          // K_DIM / BK
#define LDPE 264       // epilogue LDS leading dim (shorts)

#define GLDS16(gp, lp) __builtin_amdgcn_global_load_lds( \
    (const __attribute__((address_space(1))) void*)(gp), \
    (__attribute__((address_space(3))) void*)(lp), 16, 0, 0)

#define SBAR()   __builtin_amdgcn_s_barrier()
#define SCHED0() __builtin_amdgcn_sched_barrier(0)
#define WAIT_LGKM0() do { asm volatile("s_waitcnt lgkmcnt(0)" ::: "memory"); SCHED0(); } while(0)
#define WAIT_VM(N)   do { asm volatile("s_waitcnt vmcnt(" #N ")" ::: "memory"); SCHED0(); } while(0)

// raw ds_read_b128: no "memory" clobber (invisible to alias analysis on purpose)
#define DSR(dst, addr, IMM) \
  asm volatile("ds_read_b128 %0, %1 offset:" #IMM : "=v"(dst) : "v"(addr))

__global__ __launch_bounds__(512, 2) void gemm_gates(const unsigned short* __restrict__ Ag,
                                                     const unsigned short* __restrict__ Bg,
                                                     const float* __restrict__ bias,
                                                     unsigned short* __restrict__ u_t,
                                                     unsigned short* __restrict__ f_g,
                                                     unsigned short* __restrict__ r_g)
{
  // LDS: A dbuf = [2][256][64] shorts (bytes 0..65535), B dbuf (bytes 65536..131071)
  __shared__ unsigned short smem[65536];   // 128 KiB
  const int tid  = threadIdx.x;
  const int wave = tid >> 6, lane = tid & 63;
  const int wm = wave >> 2, wn = wave & 3;          // 2 x 4 wave grid
  const int r8 = lane >> 3;
  const int sch = (lane & 7) ^ r8;                  // inverse-swizzled source chunk
  const int fm = lane & 15, quad = lane >> 4, f7 = fm & 7;
  const int bm0 = blockIdx.x * BM, bn0 = blockIdx.y * BN;

  f32x4 zero = {0.f, 0.f, 0.f, 0.f};
  f32x4 acc[8][4];
  #pragma unroll
  for (int i = 0; i < 8; i++)
    #pragma unroll
    for (int j = 0; j < 4; j++) acc[i][j] = zero;

#define STAGE_A(BUF, T, HALF) do { \
  GLDS16(Ag + (size_t)(bm0 + (HALF)*128 + wave*16 + 0 + r8) * K_DIM + ((T)*BK + sch*8), \
         &smem[(BUF)*16384 + ((HALF)*128 + wave*16 + 0) * 64]); \
  GLDS16(Ag + (size_t)(bm0 + (HALF)*128 + wave*16 + 8 + r8) * K_DIM + ((T)*BK + sch*8), \
         &smem[(BUF)*16384 + ((HALF)*128 + wave*16 + 8) * 64]); \
} while(0)

#define STAGE_B(BUF, T, HALF) do { \
  GLDS16(Bg + (size_t)(bn0 + (HALF)*128 + wave*16 + 0 + r8) * K_DIM + ((T)*BK + sch*8), \
         &smem[32768 + (BUF)*16384 + ((HALF)*128 + wave*16 + 0) * 64]); \
  GLDS16(Bg + (size_t)(bn0 + (HALF)*128 + wave*16 + 8 + r8) * K_DIM + ((T)*BK + sch*8), \
         &smem[32768 + (BUF)*16384 + ((HALF)*128 + wave*16 + 8) * 64]); \
} while(0)

// one quadrant sub-group: 4 MFMA for output rows (MH*4+I), cols (NH*2 + 0..1)
#define MFMA4_Q(MH, NH, BREG, I) do { \
  acc[(MH)*4+(I)][(NH)*2+0] = __builtin_amdgcn_mfma_f32_16x16x32_bf16(a_[I][0], BREG[0][0], acc[(MH)*4+(I)][(NH)*2+0], 0,0,0); \
  acc[(MH)*4+(I)][(NH)*2+0] = __builtin_amdgcn_mfma_f32_16x16x32_bf16(a_[I][1], BREG[0][1], acc[(MH)*4+(I)][(NH)*2+0], 0,0,0); \
  acc[(MH)*4+(I)][(NH)*2+1] = __builtin_amdgcn_mfma_f32_16x16x32_bf16(a_[I][0], BREG[1][0], acc[(MH)*4+(I)][(NH)*2+1], 0,0,0); \
  acc[(MH)*4+(I)][(NH)*2+1] = __builtin_amdgcn_mfma_f32_16x16x32_bf16(a_[I][1], BREG[1][1], acc[(MH)*4+(I)][(NH)*2+1], 0,0,0); \
} while(0)

  bf16x8 a_[4][2], b0_[2][2], b1_[2][2];
  const unsigned slot0 = (unsigned)((quad ^ f7) << 4);
  const unsigned aBase = (unsigned)((wm * 128 + fm) * 128) + slot0;
  const unsigned bBase = 65536u + (unsigned)((wn * 64 + fm) * 128) + slot0;

  // ---- prologue: stage tile0 fully + tile1 {Bh0,Bh1,Ah0} ----
  STAGE_A(0, 0, 0); STAGE_A(0, 0, 1);
  STAGE_B(0, 0, 0); STAGE_B(0, 0, 1);
  STAGE_B(1, 1, 0); STAGE_B(1, 1, 1);
  STAGE_A(1, 1, 0);
  WAIT_VM(6);            // tile0's 8 loads landed
  SBAR();
  // pre-loop fragment reads: A0(0), B0(0) from buffer 0
  {
    unsigned qa0 = aBase, qa1 = aBase ^ 64u;
    DSR(a_[0][0], qa0, 0);    DSR(a_[0][1], qa1, 0);
    DSR(a_[1][0], qa0, 2048); DSR(a_[1][1], qa1, 2048);
    DSR(a_[2][0], qa0, 4096); DSR(a_[2][1], qa1, 4096);
    DSR(a_[3][0], qa0, 6144); DSR(a_[3][1], qa1, 6144);
    unsigned qb0 = bBase, qb1 = bBase ^ 64u;
    DSR(b0_[0][0], qb0, 0);    DSR(b0_[0][1], qb1, 0);
    DSR(b0_[1][0], qb0, 2048); DSR(b0_[1][1], qb1, 2048);
  }
  SCHED0();

  #pragma unroll
  for (int t = 0; t < NT; ++t) {
    const int cb = t & 1, nb = cb ^ 1;
    const unsigned cbB = (unsigned)(cb * 32768);
    const unsigned nbB = (unsigned)(nb * 32768);

    // -------- P0: Q00 (a_=A0 x b0_); roll B1(t); stage A(t+1)h1 --------
    WAIT_LGKM0();
    if (t + 1 < NT) STAGE_A(nb, t + 1, 1);
    SCHED0();
    __builtin_amdgcn_s_setprio(1);
    {
      unsigned q0 = cbB + bBase + 4096u, q1 = q0 ^ 64u;
      MFMA4_Q(0,0,b0_,0); SCHED0(); DSR(b1_[0][0], q0, 0);    DSR(b1_[0][1], q1, 0);    SCHED0();
      MFMA4_Q(0,0,b0_,1); SCHED0(); DSR(b1_[1][0], q0, 2048); DSR(b1_[1][1], q1, 2048); SCHED0();
      MFMA4_Q(0,0,b0_,2); SCHED0();
      MFMA4_Q(0,0,b0_,3);
    }
    __builtin_amdgcn_s_setprio(0);
    SCHED0();
    SBAR();

    // -------- P1: Q01 (a_=A0 x b1_); roll A1(t) into a_[i] after last use --------
    WAIT_LGKM0();
    __builtin_amdgcn_s_setprio(1);
    {
      unsigned q0 = cbB + aBase + 8192u, q1 = q0 ^ 64u;
      MFMA4_Q(0,1,b1_,0); SCHED0(); DSR(a_[0][0], q0, 0);    DSR(a_[0][1], q1, 0);    SCHED0();
      MFMA4_Q(0,1,b1_,1); SCHED0(); DSR(a_[1][0], q0, 2048); DSR(a_[1][1], q1, 2048); SCHED0();
      MFMA4_Q(0,1,b1_,2); SCHED0(); DSR(a_[2][0], q0, 4096); DSR(a_[2][1], q1, 4096); SCHED0();
      MFMA4_Q(0,1,b1_,3); SCHED0(); DSR(a_[3][0], q0, 6144); DSR(a_[3][1], q1, 6144); SCHED0();
    }
    __builtin_amdgcn_s_setprio(0);
    SCHED0();
    SBAR();

    // -------- P2: Q11 (a_=A1 x b1_); stage B(t+2)h0; no reads --------
    WAIT_LGKM0();
    if (t + 2 < NT) STAGE_B(cb, t + 2, 0);
    SCHED0();
    __builtin_amdgcn_s_setprio(1);
    MFMA4_Q(1,1,b1_,0); MFMA4_Q(1,1,b1_,1); MFMA4_Q(1,1,b1_,2); MFMA4_Q(1,1,b1_,3);
    __builtin_amdgcn_s_setprio(0);
    SCHED0();
    SBAR();

    // -------- P3: Q10 (a_=A1 x b0_); stage B(t+2)h1 + A(t+2)h0;
    //          WAIT_VM(6) (tile t+1 fully landed); roll A0(t+1) into a_[i];
    //          post-roll B0(t+1) into b0_ (covered by next P0's lgkm wait) --------
    if (t + 2 < NT) { STAGE_B(cb, t + 2, 1); STAGE_A(cb, t + 2, 0); }
    SCHED0();
    if (t < NT - 2)       WAIT_VM(6);
    else if (t == NT - 2) WAIT_VM(0);
    __builtin_amdgcn_s_setprio(1);
    {
      unsigned q0 = nbB + aBase, q1 = q0 ^ 64u;
      MFMA4_Q(1,0,b0_,0); SCHED0(); if (t+1 < NT) { DSR(a_[0][0], q0, 0);    DSR(a_[0][1], q1, 0);    } SCHED0();
      MFMA4_Q(1,0,b0_,1); SCHED0(); if (t+1 < NT) { DSR(a_[1][0], q0, 2048); DSR(a_[1][1], q1, 2048); } SCHED0();
      MFMA4_Q(1,0,b0_,2); SCHED0(); if (t+1 < NT) { DSR(a_[2][0], q0, 4096); DSR(a_[2][1], q1, 4096); } SCHED0();
      MFMA4_Q(1,0,b0_,3); SCHED0(); if (t+1 < NT) { DSR(a_[3][0], q0, 6144); DSR(a_[3][1], q1, 6144); } SCHED0();
    }
    __builtin_amdgcn_s_setprio(0);
    if (t + 1 < NT) {
      unsigned q0 = nbB + bBase, q1 = q0 ^ 64u;
      DSR(b0_[0][0], q0, 0);    DSR(b0_[0][1], q1, 0);
      DSR(b0_[1][0], q0, 2048); DSR(b0_[1][1], q1, 2048);
    }
    SCHED0();
    SBAR();
  }
  __syncthreads();

  // ---- epilogue: bias + activation, LDS transpose in 2 halves, coalesced out ----
  const int slice = bn0 >> 10;
  const int nd0   = bn0 & 1023;
  unsigned short* dst = (slice == 0) ? u_t : ((slice == 1) ? f_g : r_g);

  #pragma unroll
  for (int h = 0; h < 2; ++h) {
    if (wm == h) {
      #pragma unroll
      for (int ni = 0; ni < 4; ++ni) {
        int lcol = wn * 64 + ni * 16 + fm;
        float bia = bias[bn0 + lcol];
        #pragma unroll
        for (int mi = 0; mi < 8; ++mi) {
          #pragma unroll
          for (int reg = 0; reg < 4; ++reg) {
            int lrow = mi * 16 + quad * 4 + reg;          // 0..127 within half
            float v = acc[mi][ni][reg] + bia;
            float act = (slice == 0) ? ftanh(v) : fsigmoid(v);
            smem[lrow * LDPE + lcol] = f2bf(act);
          }
        }
      }
    }
    __syncthreads();
    #pragma unroll
    for (int it = 0; it < 8; ++it) {
      int row = it * 16 + (tid >> 5);
      int cc  = (tid & 31) * 8;
      u16x8 v = *(const u16x8*)&smem[row * LDPE + cc];
      *(u16x8*)(dst + (size_t)(bm0 + h * 128 + row) * DD + nd0 + cc) = v;
    }
    __syncthreads();
  }
}

// ---- scan pass 1: per-segment affine summary, vec8 channels, 16B loads ----
__global__ __launch_bounds__(256) void scan_pass1(const unsigned short* __restrict__ f_g,
                                                  const unsigned short* __restrict__ u_t,
                                                  unsigned short* __restrict__ P,
                                                  unsigned short* __restrict__ E)
{
  int vc8 = blockIdx.x * 256 + threadIdx.x;   // 0..1023
  int seg = blockIdx.y;                       // 0..127
  const u16x8* f8 = (const u16x8*)f_g;
  const u16x8* u8 = (const u16x8*)u_t;
  size_t g = (size_t)(seg * LSEG) * CH8 + vc8;
  float p[8], e[8];
  #pragma unroll
  for (int k = 0; k < 8; k++) { p[k] = 1.f; e[k] = 0.f; }
  #pragma unroll 4
  for (int i = 0; i < LSEG; i++) {
    u16x8 ff = f8[g];
    u16x8 uu = u8[g];
    #pragma unroll
    for (int k = 0; k < 8; k++) {
      float fv = bf2f(ff[k]);
      e[k] = fv * e[k] + (1.f - fv) * bf2f(uu[k]);
      p[k] *= fv;
    }
    g += CH8;
  }
  u16x8 pv, ev;
  #pragma unroll
  for (int k = 0; k < 8; k++) { pv[k] = f2bf(p[k]); ev[k] = f2bf(e[k]); }
  ((u16x8*)P)[(size_t)seg * CH8 + vc8] = pv;
  ((u16x8*)E)[(size_t)seg * CH8 + vc8] = ev;
}

// ---- scan pass 2: scan 128 segment summaries per channel ----
__global__ __launch_bounds__(128) void scan_pass2(const unsigned short* __restrict__ P,
                                                  const unsigned short* __restrict__ E,
                                                  const float* __restrict__ c0,
                                                  float* __restrict__ Cini,
                                                  float* __restrict__ lastc)
{
  int ch = blockIdx.x * 128 + threadIdx.x;    // 64 blocks x 128
  float c = c0[ch];
  #pragma unroll 8
  for (int s = 0; s < NSEG; s++) {
    Cini[(size_t)s * CH + ch] = c;
    c = bf2f(P[(size_t)s * CH + ch]) * c + bf2f(E[(size_t)s * CH + ch]);
  }
  lastc[ch] = c;
}

// ---- scan pass 3: replay with true init + fused output, vec8, 16B loads ----
__global__ __launch_bounds__(256) void scan_pass3(const unsigned short* __restrict__ f_g,
                                                  const unsigned short* __restrict__ u_t,
                                                  const unsigned short* __restrict__ r_g,
                                                  const float* __restrict__ x,
                                                  const unsigned short* __restrict__ xn,
                                                  const float* __restrict__ Cini,
                                                  float* __restrict__ out)
{
  int vc8 = blockIdx.x * 256 + threadIdx.x;   // 0..1023
  int seg = blockIdx.y;                       // 0..127
  const u16x8* f8 = (const u16x8*)f_g;
  const u16x8* u8 = (const u16x8*)u_t;
  const u16x8* r8 = (const u16x8*)r_g;
  const u16x8* n8 = (const u16x8*)xn;
  const float4* x4 = (const float4*)x;
  float4* o4 = (float4*)out;
  float c[8];
  {
    const float4* C4 = (const float4*)Cini;
    size_t ci = (size_t)seg * (CH / 4) + (size_t)vc8 * 2;
    float4 ca = C4[ci], cb = C4[ci + 1];
    c[0]=ca.x; c[1]=ca.y; c[2]=ca.z; c[3]=ca.w;
    c[4]=cb.x; c[5]=cb.y; c[6]=cb.z; c[7]=cb.w;
  }
  size_t g = (size_t)(seg * LSEG) * CH8 + vc8;
  #pragma unroll 2
  for (int i = 0; i < LSEG; i++) {
    u16x8 ff = f8[g];
    u16x8 uu = u8[g];
    u16x8 rr = r8[g];
    u16x8 nn = n8[g];
    size_t xi = g * 2;                 // float4 index (8 floats = 2 float4)
    float4 xa = x4[xi], xb = x4[xi + 1];
    float ov[8];
    #pragma unroll
    for (int k = 0; k < 8; k++) {
      float fv = bf2f(ff[k]);
      c[k] = fv * c[k] + (1.f - fv) * bf2f(uu[k]);
      float rv = bf2f(rr[k]);
      ov[k] = rv * ftanh(c[k]) + (1.f - rv) * bf2f(nn[k]);
    }
    o4[xi]     = (float4){xa.x + ov[0], xa.y + ov[1], xa.z + ov[2], xa.w + ov[3]};
    o4[xi + 1] = (float4){xb.x + ov[4], xb.y + ov[5], xb.z + ov[6], xb.w + ov[7]};
    g += CH8;
  }
}

extern "C" void kernel_launch(void* const* d_in, const int* in_sizes, int n_in,
                              void* d_out, int out_size, void* d_ws, size_t ws_size,
                              hipStream_t stream) {
  const float* x    = (const float*)d_in[0];
  const float* c0   = (const float*)d_in[1];
  const float* W    = (const float*)d_in[2];
  const float* bias = (const float*)d_in[3];
  const float* ln_g = (const float*)d_in[4];
  const float* ln_b = (const float*)d_in[5];
  float* out = (float*)d_out;

  char* ws = (char*)d_ws;
  unsigned short* xn  = (unsigned short*)(ws);                 // 33,554,432 B
  unsigned short* wb  = (unsigned short*)(ws + 33554432ULL);   //  6,291,456 B (dead after gemm)
  unsigned short* u_t = (unsigned short*)(ws + 39845888ULL);   // 33,554,432 B
  unsigned short* f_g = (unsigned short*)(ws + 73400320ULL);   // 33,554,432 B
  unsigned short* r_g = (unsigned short*)(ws + 106954752ULL);  // 33,554,432 B
  // P,E (bf16, 2 MB each) reuse wb's region after gemm completes:
  unsigned short* Pseg = (unsigned short*)(ws + 33554432ULL);  // 2,097,152 B
  unsigned short* Eseg = (unsigned short*)(ws + 35651584ULL);  // 2,097,152 B
  float* Cini = (float*)(ws + 140509184ULL);                   // 4,194,304 B (ends 144,703,488)

  ln_kernel   <<<M_DIM / 4, 256, 0, stream>>>(x, ln_g, ln_b, xn);
  wconv_kernel<<<N_DIM, 256, 0, stream>>>(W, wb);
  gemm_gates  <<<dim3(M_DIM / BM, N_DIM / BN), 512, 0, stream>>>(xn, wb, bias, u_t, f_g, r_g);
  scan_pass1  <<<dim3(CH8 / 256, NSEG), 256, 0, stream>>>(f_g, u_t, Pseg, Eseg);
  scan_pass2  <<<CH / 128, 128, 0, stream>>>(Pseg, Eseg, c0, Cini, out + (size_t)M_DIM * DD);
  scan_pass3  <<<dim3(CH8 / 256, NSEG), 256, 0, stream>>>(f_g, u_t, r_g, x, xn, Cini, out);
}